// Round 12
// baseline (274.897 us; speedup 1.0000x reference)
//
#include <hip/hip_runtime.h>

#define HIDD 1024
#define NHH  16
#define HDD  64
#define BBB  2
#define SSS  2048
#define BS   (BBB * SSS)   // 4096

typedef __attribute__((ext_vector_type(8)))  _Float16 half8;
typedef __attribute__((ext_vector_type(4)))  _Float16 half4;
typedef __attribute__((ext_vector_type(4)))  float    f32x4;
typedef __attribute__((ext_vector_type(16))) float    f32x16;

#define LSCALE 2048.0f        // 2^11: pre-scale for fp16 low part
#define LINV   (1.0f / 2048.0f)

static __device__ __forceinline__ f32x4 mfma16h(half8 a, half8 b, f32x4 c) {
    return __builtin_amdgcn_mfma_f32_16x16x32_f16(a, b, c, 0, 0, 0);
}
static __device__ __forceinline__ f32x16 mfma32h(half8 a, half8 b, f32x16 c) {
    return __builtin_amdgcn_mfma_f32_32x32x16_f16(a, b, c, 0, 0, 0);
}

// split2 fp16: v ~= h + l*2^-11, rep error ~2^-22 |v|
static __device__ __forceinline__ void split2h(float v, _Float16& h, _Float16& l) {
    h = (_Float16)v;
    l = (_Float16)((v - (float)h) * LSCALE);
}

// ---------- weight prep: W[n][d][e] f32 -> WT h/l fp16 [mat*16+n][e][d] --------------
__global__ __launch_bounds__(256) void k_wprep(const float* __restrict__ wq,
                                               const float* __restrict__ wk,
                                               const float* __restrict__ wv,
                                               _Float16* __restrict__ WTh,
                                               _Float16* __restrict__ WTl) {
    const int blk = blockIdx.x;            // mat*16 + n
    const int mat = blk >> 4, n = blk & 15;
    const float* src = (mat == 0 ? wq : mat == 1 ? wk : wv) + (size_t)n * 4096;
    for (int c = threadIdx.x; c < 4096; c += 256) {
        int e = c >> 6, d = c & 63;
        float v = src[d * 64 + e];
        _Float16 h, l;
        split2h(v, h, l);
        WTh[(size_t)blk * 4096 + c] = h;   // layout [e][d]
        WTl[(size_t)blk * 4096 + c] = l;
    }
}

// ------- per-head Q/K/V projection: 8 waves/128 rows, all 3 mats staged once ---------
__global__ __launch_bounds__(512) void k_proj_mfma(const float* __restrict__ x,
                                                   const _Float16* __restrict__ WTh,
                                                   const _Float16* __restrict__ WTl,
                                                   _Float16* __restrict__ Qh, _Float16* __restrict__ Ql,
                                                   _Float16* __restrict__ Kh, _Float16* __restrict__ Kl,
                                                   _Float16* __restrict__ VTh, _Float16* __restrict__ VTl) {
    const int n  = blockIdx.y;
    const int R0 = blockIdx.x * 128;
    const int tid = threadIdx.x;
    const int w = tid >> 6, lane = tid & 63;
    const int hi = lane >> 4, lo = lane & 15;

    __shared__ __align__(16) _Float16 smem[27648];

    half8 ah[2], al[2];
#pragma unroll
    for (int kf = 0; kf < 2; kf++) {
        const float* xp = x + (size_t)(R0 + 16 * w + lo) * HIDD + n * HDD + kf * 32 + 8 * hi;
        float4 v0 = *(const float4*)xp;
        float4 v1 = *(const float4*)(xp + 4);
        float vv[8] = { v0.x, v0.y, v0.z, v0.w, v1.x, v1.y, v1.z, v1.w };
#pragma unroll
        for (int j = 0; j < 8; ++j) {
            _Float16 h, l;
            split2h(vv[j], h, l);
            ah[kf][j] = h; al[kf][j] = l;
        }
    }

    for (int c = tid; c < 3072; c += 512) {
        int m = c >> 10, rest = c & 1023, hl = rest >> 9, cc = rest & 511;
        int r = cc >> 3, j8 = (cc & 7) << 3;
        const _Float16* src = (hl ? WTl : WTh) + ((size_t)(m * NHH + n)) * 4096 + r * 64 + j8;
        *(half8*)&smem[(m * 2 + hl) * 4608 + r * 72 + j8] = *(const half8*)src;
    }
    __syncthreads();

    const int bq = R0 >> 11;
    const int sr = R0 & 2047;
    const size_t bn = (size_t)(bq * NHH + n);
    float vkeep[4][4][2];

    for (int mat = 0; mat < 3; ++mat) {
        const _Float16* bh_base = smem + (mat * 2 + 0) * 4608;
        const _Float16* bl_base = smem + (mat * 2 + 1) * 4608;
        f32x4 a0[4], a1[4];
#pragma unroll
        for (int eb = 0; eb < 4; ++eb) {
            a0[eb] = (f32x4){0.f, 0.f, 0.f, 0.f};
            a1[eb] = (f32x4){0.f, 0.f, 0.f, 0.f};
        }
#pragma unroll
        for (int eb = 0; eb < 4; ++eb) {
            half8 bh0 = *(const half8*)&bh_base[(16 * eb + lo) * 72 + 8 * hi];
            half8 bh1 = *(const half8*)&bh_base[(16 * eb + lo) * 72 + 32 + 8 * hi];
            half8 bl0 = *(const half8*)&bl_base[(16 * eb + lo) * 72 + 8 * hi];
            half8 bl1 = *(const half8*)&bl_base[(16 * eb + lo) * 72 + 32 + 8 * hi];
            a0[eb] = mfma16h(ah[0], bh0, a0[eb]);
            a0[eb] = mfma16h(ah[1], bh1, a0[eb]);
            a1[eb] = mfma16h(ah[0], bl0, a1[eb]);
            a1[eb] = mfma16h(al[0], bh0, a1[eb]);
            a1[eb] = mfma16h(ah[1], bl1, a1[eb]);
            a1[eb] = mfma16h(al[1], bh1, a1[eb]);
        }

        if (mat < 2) {
            _Float16* Dh = (mat == 0) ? Qh : Kh;
            _Float16* Dl = (mat == 0) ? Ql : Kl;
#pragma unroll
            for (int eb = 0; eb < 4; ++eb)
#pragma unroll
                for (int r = 0; r < 4; ++r) {
                    int gr = R0 + 16 * w + 4 * hi + r;
                    int s = gr & 2047;
                    float val = a0[eb][r] + a1[eb][r] * LINV;
                    _Float16 h, l;
                    split2h(val, h, l);
                    size_t idx = (bn * SSS + s) * HDD + 16 * eb + lo;
                    Dh[idx] = h; Dl[idx] = l;
                }
        } else {
#pragma unroll
            for (int eb = 0; eb < 4; ++eb)
#pragma unroll
                for (int r = 0; r < 4; ++r) {
                    vkeep[eb][r][0] = a0[eb][r];
                    vkeep[eb][r][1] = a1[eb][r];
                }
        }
    }

    __syncthreads();
    _Float16* tbh = smem;
    _Float16* tbl = smem + 8704;
#pragma unroll
    for (int eb = 0; eb < 4; ++eb)
#pragma unroll
        for (int r = 0; r < 4; ++r) {
            int rl = 16 * w + 4 * hi + r;
            int ch = 16 * eb + lo;
            _Float16 h, l;
            split2h(vkeep[eb][r][0] + vkeep[eb][r][1] * LINV, h, l);
            tbh[ch * 136 + rl] = h;
            tbl[ch * 136 + rl] = l;
        }
    __syncthreads();
    for (int c = tid; c < 1024; c += 512) {
        int ch = c >> 4, s8 = (c & 15) << 3;
        size_t gi = (bn * HDD + ch) * SSS + sr + s8;
        *(half8*)(VTh + gi) = *(const half8*)&tbh[ch * 136 + s8];
        *(half8*)(VTl + gi) = *(const half8*)&tbl[ch * 136 + s8];
    }
}

// ---- retention: 4 waves x 32 q-rows (128/block), 32x32x16 MFMA, factored decay ------
__global__ __launch_bounds__(256) void k_ret_mfma(const _Float16* __restrict__ Qh, const _Float16* __restrict__ Ql,
                                                  const _Float16* __restrict__ Kh, const _Float16* __restrict__ Kl,
                                                  const _Float16* __restrict__ VTh, const _Float16* __restrict__ VTl,
                                                  const float* __restrict__ gns,
                                                  const float* __restrict__ gnb,
                                                  float* __restrict__ normb) {
    const int qt = (gridDim.x - 1) - blockIdx.x;   // heavy tiles first
    const int n = blockIdx.y, b = blockIdx.z;
    const int tid = threadIdx.x;
    const int w = tid >> 6, lane = tid & 63;
    const int l31 = lane & 31, lh = lane >> 5;

    const double l512 = -6.2383246250395075;   // log(1/512)
    const double l32  = -3.4657359027997265;   // log(1/32)
    double lin = l512 + (double)n * (l32 - l512) / 15.0;
    float gamma = (float)(1.0 - exp(lin));
    float l2g = log2f(gamma);                  // negative
    int dmax = (int)(16.0f / (-l2g)) + 1;      // keep gamma^d >= 2^-16

    const int qb = qt * 128;
    const int qw = qb + 32 * w;                // this wave's first q row
    int tb_start = (qb > dmax) ? ((qb - dmax) >> 6) : 0;
    const int tb_end = 2 * qt + 1;
    const int diagtb = qw >> 6;                // the one tile needing causal mask

    const size_t bn = (size_t)(b * NHH + n);
    const _Float16* Qhp = Qh + bn * SSS * HDD;
    const _Float16* Qlp = Ql + bn * SSS * HDD;
    const _Float16* Khp = Kh + bn * SSS * HDD;
    const _Float16* Klp = Kl + bn * SSS * HDD;
    const _Float16* Vhp = VTh + bn * HDD * SSS;
    const _Float16* Vlp = VTl + bn * HDD * SSS;

    // Q A-fragments (32x32x16): row = qw + l31, k(d) = 8*lh + j + 16*st
    half8 qfh[4], qfl[4];
#pragma unroll
    for (int st = 0; st < 4; ++st) {
        size_t o = (size_t)(qw + l31) * HDD + 16 * st + 8 * lh;
        qfh[st] = *(const half8*)(Qhp + o);
        qfl[st] = *(const half8*)(Qlp + o);
    }

    // factored decay: gamma^(qg-tg) = fq[row] * ft[colblock]
    const float ft0 = exp2f(-(float)l31 * l2g);
    const float ft1 = exp2f(-(float)(32 + l31) * l2g);
    float fq[16];
#pragma unroll
    for (int r = 0; r < 16; ++r) {
        int ql = (r & 3) + 8 * (r >> 2) + 4 * lh;   // C-frag row map (verified)
        fq[r] = exp2f((float)(qw + ql - tb_start * 64) * l2g);
    }
    const float ginv64 = exp2f(-64.0f * l2g);

    f32x16 acc0[2], acc1[2];
#pragma unroll
    for (int e = 0; e < 2; ++e)
#pragma unroll
        for (int r = 0; r < 16; ++r) { acc0[e][r] = 0.f; acc1[e][r] = 0.f; }

    // K/V: linear stride 64, XOR-swizzled 16B slots. P: per-wave [32][72] h/l.
    __shared__ __align__(16) _Float16 ksh[64 * 64];
    __shared__ __align__(16) _Float16 ksl[64 * 64];
    __shared__ __align__(16) _Float16 vsh[64 * 64];
    __shared__ __align__(16) _Float16 vsl[64 * 64];
    __shared__ __align__(16) _Float16 psh[4 * 32 * 72];
    __shared__ __align__(16) _Float16 psl[4 * 32 * 72];

    half8 pre[8];
    auto issue = [&](int tbase) {
#pragma unroll
        for (int i = 0; i < 8; ++i) {
            int c = tid + (i << 8);
            int which = c >> 9, cc = c & 511, r = cc >> 3, j8 = (cc & 7) << 3;
            const _Float16* src =
                which == 0 ? Khp + (size_t)(tbase + r) * HDD + j8 :
                which == 1 ? Klp + (size_t)(tbase + r) * HDD + j8 :
                which == 2 ? Vhp + (size_t)r * SSS + tbase + j8 :
                             Vlp + (size_t)r * SSS + tbase + j8;
            pre[i] = *(const half8*)src;
        }
    };
    auto commit = [&]() {
#pragma unroll
        for (int i = 0; i < 8; ++i) {
            int c = tid + (i << 8);
            int which = c >> 9, cc = c & 511, r = cc >> 3, j = cc & 7;
            int doff = r * 64 + ((j ^ (r & 7)) << 3);
            _Float16* dst = which == 0 ? ksh : which == 1 ? ksl : which == 2 ? vsh : vsl;
            *(half8*)&dst[doff] = pre[i];
        }
    };

    issue(tb_start * 64);
    commit();
    __syncthreads();

    for (int tb = tb_start; tb <= tb_end; ++tb) {
        const int tbase = tb * 64;
        if (tb < tb_end) issue(tbase + 64);

        const bool active = (tbase <= qw + 31) && (tbase + 63 >= qw - dmax);
        if (active) {
            // ---- QK^T: 32x32x16, split fp16, per col-block of 32 t ----
#pragma unroll
            for (int cb = 0; cb < 2; ++cb) {
                const int trow = 32 * cb + l31;          // B col = t (frag col = l31)
                f32x16 s0, s1;
#pragma unroll
                for (int r = 0; r < 16; ++r) { s0[r] = 0.f; s1[r] = 0.f; }
#pragma unroll
                for (int st = 0; st < 4; ++st) {
                    int slot = ((2 * st + lh) ^ (trow & 7)) << 3;
                    const int ka = trow * 64 + slot;
                    half8 kh = *(const half8*)&ksh[ka];
                    half8 kl = *(const half8*)&ksl[ka];
                    s0 = mfma32h(qfh[st], kh, s0);
                    s1 = mfma32h(qfh[st], kl, s1);
                    s1 = mfma32h(qfl[st], kh, s1);
                }
                const float ftc = cb ? ft1 : ft0;
                const bool dm = (tb == diagtb);
#pragma unroll
                for (int r = 0; r < 16; ++r) {
                    int ql = (r & 3) + 8 * (r >> 2) + 4 * lh;
                    float p = (s0[r] + s1[r] * LINV) * (fq[r] * ftc);
                    if (dm) {
                        int diff = (qw + ql) - (tbase + trow);
                        p = (diff >= 0) ? p : 0.0f;
                    }
                    _Float16 ph, pl;
                    split2h(p, ph, pl);
                    int slot2 = ((((trow >> 3) ^ (ql & 7)) << 3)) + (trow & 7);
                    int pidx = w * 2304 + ql * 72 + slot2;
                    psh[pidx] = ph;
                    psl[pidx] = pl;
                }
            }
            // ---- PV: 32x32x16 (per-wave P: same-wave LDS dep, no barrier) ----
#pragma unroll
            for (int eb = 0; eb < 2; ++eb) {
                const int chrow = 32 * eb + l31;         // B col = ch
#pragma unroll
                for (int st = 0; st < 4; ++st) {
                    int tcol = 8 * lh + 16 * st;         // A k = t
                    int pslot = (((tcol >> 3) ^ (l31 & 7)) << 3);
                    int pa = w * 2304 + l31 * 72 + pslot;
                    half8 p8h = *(const half8*)&psh[pa];
                    half8 p8l = *(const half8*)&psl[pa];
                    int vslot = ((2 * st + lh) ^ (chrow & 7)) << 3;
                    int va = chrow * 64 + vslot;
                    half8 vh = *(const half8*)&vsh[va];
                    half8 vl = *(const half8*)&vsl[va];
                    acc0[eb] = mfma32h(p8h, vh, acc0[eb]);
                    acc1[eb] = mfma32h(p8h, vl, acc1[eb]);
                    acc1[eb] = mfma32h(p8l, vh, acc1[eb]);
                }
            }
        }
#pragma unroll
        for (int r = 0; r < 16; ++r) fq[r] *= ginv64;

        __syncthreads();                 // all waves done reading current tile
        if (tb < tb_end) commit();       // write prefetched next tile
        __syncthreads();                 // staging visible before next compute
    }

    // combine scaled-low accumulator
    f32x16 accf[2];
#pragma unroll
    for (int e = 0; e < 2; ++e)
#pragma unroll
        for (int r = 0; r < 16; ++r)
            accf[e][r] = acc0[e][r] + acc1[e][r] * LINV;

    // ---- fused GroupNorm on 32x32 C-frag: row = (r&3)+8(r>>2)+4lh, col = 32eb+l31 ----
    float s[16], sq[16];
#pragma unroll
    for (int r = 0; r < 16; ++r) {
        float v0 = accf[0][r], v1 = accf[1][r];
        s[r] = v0 + v1;
        sq[r] = v0 * v0 + v1 * v1;
    }
#pragma unroll
    for (int mask = 1; mask < 32; mask <<= 1)
#pragma unroll
        for (int r = 0; r < 16; ++r) {
            s[r]  += __shfl_xor(s[r],  mask);
            sq[r] += __shfl_xor(sq[r], mask);
        }
#pragma unroll
    for (int e = 0; e < 2; ++e)
#pragma unroll
        for (int r = 0; r < 16; ++r) {
            float mean = s[r] * (1.0f / 64.0f);
            float var  = sq[r] * (1.0f / 64.0f) - mean * mean;
            float rstd = rsqrtf(var + 1e-5f);
            int ql = (r & 3) + 8 * (r >> 2) + 4 * lh;
            int ch = 32 * e + l31;
            int sg = qw + ql;
            float nv = (accf[e][r] - mean) * rstd;
            nv = nv * gns[n * 64 + ch] + gnb[n * 64 + ch];
            normb[((size_t)b * SSS + sg) * HIDD + n * 64 + ch] = nv;
        }
}

// ---------------- f32 -> fp16 cast ----------------
__global__ __launch_bounds__(256) void k_cvt_h(const float* __restrict__ src,
                                               _Float16* __restrict__ dst) {
    int i = blockIdx.x * 256 + threadIdx.x;
    float4 v = reinterpret_cast<const float4*>(src)[i];
    half4 o = { (_Float16)v.x, (_Float16)v.y, (_Float16)v.z, (_Float16)v.w };
    reinterpret_cast<half4*>(dst)[i] = o;
}

// ------------- transpose f32 [K][N] -> fp16 [N][K] -------------
__global__ __launch_bounds__(256) void k_tr_h(const float* __restrict__ src,
                                              _Float16* __restrict__ dst,
                                              int K, int N) {
    __shared__ float ls[32][33];
    int kb = blockIdx.y * 32, nb = blockIdx.x * 32;
    int tx = threadIdx.x & 31, ty = threadIdx.x >> 5;   // 32 x 8
#pragma unroll
    for (int i = 0; i < 4; i++) {
        int r = ty + 8 * i;
        ls[r][tx] = src[(size_t)(kb + r) * N + nb + tx];
    }
    __syncthreads();
#pragma unroll
    for (int i = 0; i < 4; i++) {
        int r = ty + 8 * i;
        dst[(size_t)(nb + r) * K + kb + tx] = (_Float16)ls[tx][r];
    }
}

// ------- 128x128 single-fp16 MFMA GEMM with reg-prefetch staging ---------------------
template <int MODE>
__global__ __launch_bounds__(256) void k_gemm_h(const _Float16* __restrict__ A,
                                                const _Float16* __restrict__ Bt,
                                                const float* __restrict__ normb,
                                                _Float16* __restrict__ Y,
                                                float* __restrict__ Out) {
    const int Rb = blockIdx.x * 128, Cb = blockIdx.y * 128;
    const int tid = threadIdx.x, w = tid >> 6, lane = tid & 63;
    const int hi = lane >> 4, lo = lane & 15;
    const int wm = w >> 1, wn = w & 1;

    __shared__ __align__(16) _Float16 as[128 * 40];
    __shared__ __align__(16) _Float16 bs[128 * 40];

    f32x4 acc[4][4];
#pragma unroll
    for (int m = 0; m < 4; m++)
#pragma unroll
        for (int nn = 0; nn < 4; nn++) acc[m][nn] = (f32x4){0.f, 0.f, 0.f, 0.f};

    half8 pre[4];
    auto g_issue = [&](int kk) {
#pragma unroll
        for (int i = 0; i < 4; ++i) {
            int c = tid + (i << 8);
            int which = c >> 9, cc = c & 511, row = cc >> 2, j8 = (cc & 3) << 3;
            const _Float16* src = (which == 0)
                ? A  + (size_t)(Rb + row) * HIDD + kk * 32 + j8
                : Bt + (size_t)(Cb + row) * HIDD + kk * 32 + j8;
            pre[i] = *(const half8*)src;
        }
    };
    auto g_commit = [&]() {
#pragma unroll
        for (int i = 0; i < 4; ++i) {
            int c = tid + (i << 8);
            int which = c >> 9, cc = c & 511, row = cc >> 2, j8 = (cc & 3) << 3;
            _Float16* dst = (which == 0) ? as : bs;
            *(half8*)&dst[row * 40 + j8] = pre[i];
        }
    };

    g_issue(0);
    g_commit();
    __syncthreads();

    for (int kk = 0; kk < 32; ++kk) {
        if (kk < 31) g_issue(kk + 1);
        half8 af[4], bf[4];
#pragma unroll
        for (int m = 0; m < 4; m++)
            af[m] = *(const half8*)&as[(64 * wm + 16 * m + lo) * 40 + 8 * hi];
#pragma unroll
        for (int nn = 0; nn < 4; nn++)
            bf[nn] = *(const half8*)&bs[(64 * wn + 16 * nn + lo) * 40 + 8 * hi];
#pragma unroll
        for (int m = 0; m < 4; m++)
#pragma unroll
            for (int nn = 0; nn < 4; nn++)
                acc[m][nn] = mfma16h(af[m], bf[nn], acc[m][nn]);
        __syncthreads();
        if (kk < 31) g_commit();
        __syncthreads();
    }

#pragma unroll
    for (int m = 0; m < 4; m++)
#pragma unroll
        for (int nn = 0; nn < 4; nn++)
#pragma unroll
            for (int r = 0; r < 4; r++) {
                int row = Rb + 64 * wm + 16 * m + 4 * hi + r;
                int col = Cb + 64 * wn + 16 * nn + lo;
                float v = acc[m][nn][r];
                size_t idx = (size_t)row * HIDD + col;
                if (MODE == 0) {
                    float sw = v / (1.0f + expf(-v));
                    float y = sw + normb[idx];
                    Y[idx] = (_Float16)y;
                } else {
                    Out[idx] = v;
                }
            }
}

// ------------------------------------------------------------------------------------
extern "C" void kernel_launch(void* const* d_in, const int* in_sizes, int n_in,
                              void* d_out, int out_size, void* d_ws, size_t ws_size,
                              hipStream_t stream) {
    const float* x   = (const float*)d_in[0];
    const float* wq  = (const float*)d_in[1];
    const float* wk  = (const float*)d_in[2];
    const float* wv  = (const float*)d_in[3];
    const float* w1  = (const float*)d_in[4];
    const float* w2  = (const float*)d_in[5];
    const float* gns = (const float*)d_in[6];
    const float* gnb = (const float*)d_in[7];
    float* out = (float*)d_out;

    // ---- workspace: the proven 64 MiB footprint ----
    char* base = (char*)d_ws;
    size_t off = 0;
    auto carve = [&](size_t bytes) -> void* {
        void* p = base + off;
        off += (bytes + 255) & ~(size_t)255;
        return p;
    };
    _Float16* Qh  = (_Float16*)carve((size_t)BS * HIDD * 2);   // 8 MiB
    _Float16* Ql  = (_Float16*)carve((size_t)BS * HIDD * 2);   // 8 MiB
    _Float16* Kh  = (_Float16*)carve((size_t)BS * HIDD * 2);   // 8 MiB
    _Float16* Kl  = (_Float16*)carve((size_t)BS * HIDD * 2);   // 8 MiB
    _Float16* VTh = (_Float16*)carve((size_t)BS * HIDD * 2);   // 8 MiB
    _Float16* VTl = (_Float16*)carve((size_t)BS * HIDD * 2);   // 8 MiB
    float*    normb = (float*)carve((size_t)BS * HIDD * 4);    // 16 MiB => 64 MiB
    // aliases:
    _Float16* WTh = (_Float16*)normb;                 // 384 KiB (normb written later)
    _Float16* WTl = WTh + (size_t)48 * 4096;          // 384 KiB
    _Float16* xh  = Qh;                               // after k_ret: Q dead
    _Float16* w1t = Kh;                               // after k_ret: K dead
    _Float16* w2t = Kh + (size_t)HIDD * HIDD;
    _Float16* yh  = VTh;                              // after k_ret: VT dead
    (void)ws_size; (void)in_sizes; (void)n_in; (void)out_size;

    // 0) weight prep
    k_wprep<<<48, 256, 0, stream>>>(wq, wk, wv, WTh, WTl);
    // 1) projections
    k_proj_mfma<<<dim3(BS / 128, NHH), 512, 0, stream>>>(x, WTh, WTl,
                                                         Qh, Ql, Kh, Kl, VTh, VTl);
    // 2) retention: 128-row blocks, 32x32x16 MFMA, factored decay
    k_ret_mfma<<<dim3(SSS / 128, NHH, BBB), 256, 0, stream>>>(Qh, Ql, Kh, Kl, VTh, VTl,
                                                              gns, gnb, normb);
    // 3) GEMM operand prep
    k_cvt_h<<<(BS * HIDD) / 4 / 256, 256, 0, stream>>>(x, xh);
    k_tr_h<<<dim3(32, 32), 256, 0, stream>>>(w1, w1t, HIDD, HIDD);
    k_tr_h<<<dim3(32, 32), 256, 0, stream>>>(w2, w2t, HIDD, HIDD);
    // 4) gate GEMM + swish + add norm
    k_gemm_h<0><<<dim3(BS / 128, HIDD / 128), 256, 0, stream>>>(xh, w1t, normb, yh, nullptr);
    // 5) final GEMM -> out f32
    k_gemm_h<1><<<dim3(BS / 128, HIDD / 128), 256, 0, stream>>>(yh, w2t, nullptr, nullptr, out);
}